// Round 7
// baseline (601.187 us; speedup 1.0000x reference)
//
#include <hip/hip_runtime.h>
#include <hip/hip_bf16.h>

#define H 4096
#define NEXP 256
#define TOPK 8
#define NGROUP 8
#define TOPKG 4
#define ROUTED_SCALING 2.5f
#define WSCALE 1024.0f
#define INV_WSCALE (1.0 / 1024.0)

typedef __attribute__((ext_vector_type(8)))  _Float16 f16x8;
typedef __attribute__((ext_vector_type(16))) float    f32x16;
typedef __attribute__((ext_vector_type(4)))  float    f32x4;   // clang vector: OK for nontemporal builtin

// ============================================================================
// Pre-kernel: split W*1024 [256][4096] fp32 into 2 fp16 levels (hi + exact
// residual), stored in mfma_f32_32x32x16_f16 B-fragment order.
//   level v at byte offset v*2097152 (2 MB each, 4 MB total)
//   frag addr = v*2097152 + ((etile*256 + ks)*64 + lane)*16
//   lane l holds W[etile*32 + (l&31)][16*ks + 8*(l>>5) + j], j=0..7
// Scaling by 2^10 keeps level-2 out of fp16 subnormal range (w'~16 ->
// w2'~4e-3 normal); without it w2~4e-6 is subnormal => ~17 useful bits.
// ============================================================================
__global__ __launch_bounds__(256) void wsplit_kernel(
    const float* __restrict__ W, char* __restrict__ ws)
{
    const int t  = blockIdx.x * 256 + threadIdx.x;   // 0..131071
    const int l  = t & 63;
    const int ks = (t >> 6) & 255;
    const int eg = t >> 14;                          // expert tile 0..7
    const int expert = eg * 32 + (l & 31);
    const int k0 = ks * 16 + (l >> 5) * 8;
    const float* src = W + (size_t)expert * H + k0;
    float xf[8];
    *(float4*)&xf[0] = *(const float4*)(src);
    *(float4*)&xf[4] = *(const float4*)(src + 4);
    union { _Float16 h[8]; int4 q; } o1, o2;
#pragma unroll
    for (int j = 0; j < 8; ++j) {
        const float x = xf[j] * WSCALE;
        const _Float16 h1 = (_Float16)x;
        const float r1 = x - (float)h1;
        o1.h[j] = h1;
        o2.h[j] = (_Float16)r1;
    }
    const size_t off = ((size_t)((eg * 256 + ks) * 64 + l)) * 16;
    *(int4*)(ws + off)           = o1.q;
    *(int4*)(ws + 2097152 + off) = o2.q;
}

// ============================================================================
// Main kernel: 256 blocks x 512 threads. Block = 64 tokens x 256 experts.
// Wave = 32 tok x 64 exp. K-loop: no LDS/barriers. A: nontemporal global fp32
// -> 2-level fp16 split in registers (4-deep prefetch; nt keeps X from
// evicting the 4MB W-frag set out of per-XCD L2). B: frag fp16, 2-deep.
// 3 products per K-step: x1w1 -> acc_hi (chunk-drained to fp64 every 8 ks),
// x1w2 + x2w1 -> acc_rest chain (2^-11 relative scale -> noise negligible).
// ============================================================================
__global__ __launch_bounds__(512, 2) void moe_mfma_kernel(
    const float* __restrict__ X, const char* __restrict__ ws,
    const float* __restrict__ bias, float* __restrict__ out, int T)
{
    __shared__ float SC[NEXP * 32];   // 32 KB, epilogue only
    const int tid = threadIdx.x;
    const int l   = tid & 63;
    const int wid = tid >> 6;        // 0..7
    const int tg  = wid & 1;         // token group
    const int eg  = wid >> 1;        // expert group 0..3
    const int m0  = blockIdx.x * 64;

    const float* Xp = X + (size_t)(m0 + 32 * tg + (l & 31)) * H + 8 * (l >> 5);
    const char* bp0 = ws + (size_t)(2 * eg)     * 262144 + (size_t)l * 16;
    const char* bp1 = ws + (size_t)(2 * eg + 1) * 262144 + (size_t)l * 16;

    f32x16 acc_hi[2], acc_rest[2];
    double tot[2][16];
#pragma unroll
    for (int et = 0; et < 2; ++et) {
#pragma unroll
        for (int r = 0; r < 16; ++r) {
            acc_hi[et][r] = 0.f; acc_rest[et][r] = 0.f; tot[et][r] = 0.0;
        }
    }

    f32x4 ra[4][2];                  // A fp32, 4-deep (clang vectors)
    union BF { int4 q; f16x8 v; };
    BF rb[2][4];                     // B frags, 2-deep; idx = 2*v + et
    union AF { f16x8 v; _Float16 h[8]; };

#define LOADA(ks, sa)                                                     \
    { ra[sa][0] =                                                         \
          __builtin_nontemporal_load((const f32x4*)(Xp + 16 * (ks)));     \
      ra[sa][1] =                                                         \
          __builtin_nontemporal_load((const f32x4*)(Xp + 16 * (ks) + 4)); }
#define LOADB(ks, sb)                                                     \
    { _Pragma("unroll")                                                   \
      for (int v = 0; v < 2; ++v) {                                       \
        rb[sb][2*v+0].q = *(const int4*)(bp0 + v * 2097152 + (ks) * 1024);\
        rb[sb][2*v+1].q = *(const int4*)(bp1 + v * 2097152 + (ks) * 1024);\
      } }

    LOADA(0, 0) LOADA(1, 1) LOADA(2, 2) LOADA(3, 3)
    LOADB(0, 0) LOADB(1, 1)

#define STEP(ks, sa, sb)                                                  \
    {   AF af1, af2;                                                      \
        _Pragma("unroll")                                                 \
        for (int j = 0; j < 8; ++j) {                                     \
            const float x = ra[sa][j >> 2][j & 3];                        \
            const _Float16 h1 = (_Float16)x;                              \
            const float r1 = x - (float)h1;                               \
            af1.h[j] = h1;                                                \
            af2.h[j] = (_Float16)r1;                                      \
        }                                                                 \
        _Pragma("unroll")                                                 \
        for (int et = 0; et < 2; ++et) {                                  \
            acc_hi[et] = __builtin_amdgcn_mfma_f32_32x32x16_f16(          \
                af1.v, rb[sb][et].v, acc_hi[et], 0, 0, 0);                \
            acc_rest[et] = __builtin_amdgcn_mfma_f32_32x32x16_f16(        \
                af1.v, rb[sb][2 + et].v, acc_rest[et], 0, 0, 0);          \
            acc_rest[et] = __builtin_amdgcn_mfma_f32_32x32x16_f16(        \
                af2.v, rb[sb][et].v, acc_rest[et], 0, 0, 0);              \
        }                                                                 \
        if ((ks) + 4 < 256) LOADA((ks) + 4, sa)                           \
        if ((ks) + 2 < 256) LOADB((ks) + 2, sb)                           \
    }

    for (int k8 = 0; k8 < 256; k8 += 8) {
        STEP(k8 + 0, 0, 0)
        STEP(k8 + 1, 1, 1)
        STEP(k8 + 2, 2, 0)
        STEP(k8 + 3, 3, 1)
        STEP(k8 + 4, 0, 0)
        STEP(k8 + 5, 1, 1)
        STEP(k8 + 6, 2, 0)
        STEP(k8 + 7, 3, 1)
        // drain chunk (K=128) into fp64 totals; reset chunk accumulator
#pragma unroll
        for (int et = 0; et < 2; ++et) {
#pragma unroll
            for (int r = 0; r < 16; ++r) {
                tot[et][r] += (double)acc_hi[et][r];
                acc_hi[et][r] = 0.f;
            }
        }
    }
#undef STEP
#undef LOADA
#undef LOADB

    // ---- epilogue: two 32-token phases ----
    for (int ph = 0; ph < 2; ++ph) {
        if (tg == ph) {
#pragma unroll
            for (int et = 0; et < 2; ++et) {
                const int e = 64 * eg + 32 * et + (l & 31);
                const float be = bias[e];
#pragma unroll
                for (int r = 0; r < 16; ++r) {
                    const int ti = (r & 3) + 8 * (r >> 2) + 4 * (l >> 5);
                    const float logit = (float)(
                        (tot[et][r] + (double)acc_rest[et][r]) * INV_WSCALE);
                    const float s = 1.0f / (1.0f + expf(-logit));
                    SC[e * 32 + (ti ^ (e & 31))] = s + be;
                }
            }
        }
        __syncthreads();
        if (tid < 32) {
            const int t = tid;
            float gs[NGROUP];
#pragma unroll
            for (int g = 0; g < NGROUP; ++g) {
                float m1 = -1e30f, m2 = -1e30f;
                for (int j = 0; j < 32; ++j) {
                    const int e = g * 32 + j;
                    const float v = SC[e * 32 + (t ^ (e & 31))];
                    if (v > m1) { m2 = m1; m1 = v; }
                    else if (v > m2) { m2 = v; }
                }
                gs[g] = m1 + m2;
            }
            unsigned gmask = 0;
            for (int r = 0; r < TOPKG; ++r) {
                int bi = 0; float bv = -1e30f;
#pragma unroll
                for (int g = 0; g < NGROUP; ++g)
                    if (!((gmask >> g) & 1u) && gs[g] > bv) { bv = gs[g]; bi = g; }
                gmask |= (1u << bi);
            }
            int glist[TOPKG], ng = 0;
#pragma unroll
            for (int g = 0; g < NGROUP; ++g)
                if ((gmask >> g) & 1u) glist[ng++] = g;
            int eidx[TOPK]; float sval[TOPK];
            unsigned cmask[TOPKG] = {0u, 0u, 0u, 0u};
            float wsum = 0.f;
            for (int r = 0; r < TOPK; ++r) {
                float bv = -1e30f; int bgi = 0, bj = 0;
                for (int gi = 0; gi < TOPKG; ++gi) {
                    const int g = glist[gi];
                    for (int j = 0; j < 32; ++j) {
                        if ((cmask[gi] >> j) & 1u) continue;
                        const int e = g * 32 + j;
                        const float v = SC[e * 32 + (t ^ (e & 31))];
                        if (v > bv) { bv = v; bgi = gi; bj = j; }
                    }
                }
                cmask[bgi] |= (1u << bj);
                const int e = glist[bgi] * 32 + bj;
                eidx[r] = e;
                const float sig = bv - bias[e];
                sval[r] = sig; wsum += sig;
            }
            const float scale = ROUTED_SCALING / (wsum + 1e-20f);
            const size_t gt = (size_t)(m0 + 32 * ph + t);
#pragma unroll
            for (int r = 0; r < TOPK; ++r) {
                out[gt * TOPK + r] = (float)eidx[r];
                out[(size_t)T * TOPK + gt * TOPK + r] = sval[r] * scale;
            }
        }
        __syncthreads();
    }
}

// ============================================================================
// Fallback (verified round-3 fp32 kernel) if ws is too small for the split-W.
// ============================================================================
#define BMF 32
#define BKF 32
#define WS_STRIDE 388
#define XS_STRIDE 36
#define WS_FLOATS (BKF * WS_STRIDE)
#define SMEM_FLOATS (WS_FLOATS + BKF * XS_STRIDE)

__global__ __launch_bounds__(256, 2) void moe_gate_f32(
    const float* __restrict__ X, const float* __restrict__ W,
    const float* __restrict__ bias, float* __restrict__ out, int T)
{
    __shared__ float smem[SMEM_FLOATS];
    float* Ws = smem;
    float* Xs = smem + WS_FLOATS;
    float* SC = smem;
    const int tid = threadIdx.x;
    const int tq  = tid >> 5;
    const int tx  = tid & 31;
    const int m0  = blockIdx.x * BMF;
    const int q  = tid & 7;
    const int sx = tid >> 3;
    float acc[4][8];
#pragma unroll
    for (int r = 0; r < 4; ++r)
#pragma unroll
        for (int c = 0; c < 8; ++c) acc[r][c] = 0.f;
    float4 xr, wr[8];
    const float* Xbase = X + (size_t)(m0 + sx) * H + 4 * q;
    const float* Wbase = W + (size_t)sx * H + 4 * q;
    auto loadTile = [&](int k0) {
        xr = *(const float4*)(Xbase + k0);
#pragma unroll
        for (int i = 0; i < 8; ++i)
            wr[i] = *(const float4*)(Wbase + (size_t)(32 * i) * H + k0);
    };
    auto storeTile = [&]() {
        Xs[(4 * q + 0) * XS_STRIDE + sx] = xr.x;
        Xs[(4 * q + 1) * XS_STRIDE + sx] = xr.y;
        Xs[(4 * q + 2) * XS_STRIDE + sx] = xr.z;
        Xs[(4 * q + 3) * XS_STRIDE + sx] = xr.w;
#pragma unroll
        for (int i = 0; i < 8; ++i) {
            const int e = sx + 32 * i;
            const int col = 12 * (e >> 3) + (e & 7);
            Ws[(4 * q + 0) * WS_STRIDE + col] = wr[i].x;
            Ws[(4 * q + 1) * WS_STRIDE + col] = wr[i].y;
            Ws[(4 * q + 2) * WS_STRIDE + col] = wr[i].z;
            Ws[(4 * q + 3) * WS_STRIDE + col] = wr[i].w;
        }
    };
    loadTile(0);
    for (int k0 = 0; k0 < H; k0 += BKF) {
        storeTile();
        __syncthreads();
        if (k0 + BKF < H) loadTile(k0 + BKF);
#pragma unroll 8
        for (int kk = 0; kk < BKF; ++kk) {
            float a[4], b[8];
            *(float4*)&a[0] = *(const float4*)&Xs[kk * XS_STRIDE + 4 * tq];
            *(float4*)&b[0] = *(const float4*)&Ws[kk * WS_STRIDE + 12 * tx];
            *(float4*)&b[4] = *(const float4*)&Ws[kk * WS_STRIDE + 12 * tx + 4];
#pragma unroll
            for (int r = 0; r < 4; ++r)
#pragma unroll
                for (int c = 0; c < 8; ++c)
                    acc[r][c] = fmaf(a[r], b[c], acc[r][c]);
        }
        __syncthreads();
    }
#pragma unroll
    for (int c = 0; c < 8; ++c) {
        const int e = 8 * tx + c;
        const float be = bias[e];
#pragma unroll
        for (int r = 0; r < 4; ++r) {
            const int t = 4 * tq + r;
            const float s = 1.0f / (1.0f + expf(-acc[r][c]));
            SC[e * 32 + (t ^ tx)] = s + be;
        }
    }
    __syncthreads();
    if (tid < BMF) {
        const int t = tid;
        float gs[NGROUP];
#pragma unroll
        for (int g = 0; g < NGROUP; ++g) {
            float m1 = -1e30f, m2 = -1e30f;
            for (int j = 0; j < 32; ++j) {
                const int e = g * 32 + j;
                const float v = SC[e * 32 + (t ^ (e >> 3))];
                if (v > m1) { m2 = m1; m1 = v; }
                else if (v > m2) { m2 = v; }
            }
            gs[g] = m1 + m2;
        }
        unsigned gmask = 0;
        for (int r = 0; r < TOPKG; ++r) {
            int bi = 0; float bv = -1e30f;
#pragma unroll
            for (int g = 0; g < NGROUP; ++g)
                if (!((gmask >> g) & 1u) && gs[g] > bv) { bv = gs[g]; bi = g; }
            gmask |= (1u << bi);
        }
        int glist[TOPKG], ng = 0;
#pragma unroll
        for (int g = 0; g < NGROUP; ++g)
            if ((gmask >> g) & 1u) glist[ng++] = g;
        int eidx[TOPK]; float sval[TOPK];
        unsigned cmask[TOPKG] = {0u, 0u, 0u, 0u};
        float wsum = 0.f;
        for (int r = 0; r < TOPK; ++r) {
            float bv = -1e30f; int bgi = 0, bj = 0;
            for (int gi = 0; gi < TOPKG; ++gi) {
                const int g = glist[gi];
                for (int j = 0; j < 32; ++j) {
                    if ((cmask[gi] >> j) & 1u) continue;
                    const int e = g * 32 + j;
                    const float v = SC[e * 32 + (t ^ (e >> 3))];
                    if (v > bv) { bv = v; bgi = gi; bj = j; }
                }
            }
            cmask[bgi] |= (1u << bj);
            const int e = glist[bgi] * 32 + bj;
            eidx[r] = e;
            const float sig = bv - bias[e];
            sval[r] = sig; wsum += sig;
        }
        const float scale = ROUTED_SCALING / (wsum + 1e-20f);
        const size_t gt = (size_t)(m0 + t);
#pragma unroll
        for (int r = 0; r < TOPK; ++r) {
            out[gt * TOPK + r] = (float)eidx[r];
            out[(size_t)T * TOPK + gt * TOPK + r] = sval[r] * scale;
        }
    }
}

extern "C" void kernel_launch(void* const* d_in, const int* in_sizes, int n_in,
                              void* d_out, int out_size, void* d_ws, size_t ws_size,
                              hipStream_t stream) {
    const float* X = (const float*)d_in[0];
    const float* W = (const float*)d_in[1];
    const float* B = (const float*)d_in[2];
    float* out = (float*)d_out;
    const int T = in_sizes[0] / H;            // 16384
    if (ws_size >= (size_t)4 * 1024 * 1024) {
        wsplit_kernel<<<512, 256, 0, stream>>>(W, (char*)d_ws);
        moe_mfma_kernel<<<T / 64, 512, 0, stream>>>(X, (const char*)d_ws, B, out, T);
    } else {
        moe_gate_f32<<<T / 32, 256, 0, stream>>>(X, W, B, out, T);
    }
}

// Round 8
// 246.669 us; speedup vs baseline: 2.4372x; 2.4372x over previous
//
#include <hip/hip_runtime.h>
#include <hip/hip_bf16.h>

#define H 4096
#define NEXP 256
#define TOPK 8
#define NGROUP 8
#define TOPKG 4
#define ROUTED_SCALING 2.5f
#define WSCALE 1024.0f
#define INV_WSCALE (1.0f / 1024.0f)

typedef __attribute__((ext_vector_type(8)))  _Float16 f16x8;
typedef __attribute__((ext_vector_type(16))) float    f32x16;
typedef __attribute__((ext_vector_type(4)))  float    f32x4;

// ============================================================================
// Pre-kernel: split W*1024 [256][4096] fp32 into 2 fp16 levels (hi + exact
// residual), stored in mfma_f32_32x32x16_f16 B-fragment order.
//   level v at byte offset v*2097152 (2 MB each, 4 MB total -> fits per-XCD L2)
//   frag addr = v*2097152 + ((etile*256 + ks)*64 + lane)*16
//   lane l holds W[etile*32 + (l&31)][16*ks + 8*(l>>5) + j], j=0..7
// ============================================================================
__global__ __launch_bounds__(256) void wsplit_kernel(
    const float* __restrict__ W, char* __restrict__ ws)
{
    const int t  = blockIdx.x * 256 + threadIdx.x;   // 0..131071
    const int l  = t & 63;
    const int ks = (t >> 6) & 255;
    const int eg = t >> 14;                          // expert tile 0..7
    const int expert = eg * 32 + (l & 31);
    const int k0 = ks * 16 + (l >> 5) * 8;
    const float* src = W + (size_t)expert * H + k0;
    float xf[8];
    *(float4*)&xf[0] = *(const float4*)(src);
    *(float4*)&xf[4] = *(const float4*)(src + 4);
    union { _Float16 h[8]; int4 q; } o1, o2;
#pragma unroll
    for (int j = 0; j < 8; ++j) {
        const float x = xf[j] * WSCALE;
        const _Float16 h1 = (_Float16)x;
        o1.h[j] = h1;
        o2.h[j] = (_Float16)(x - (float)h1);
    }
    const size_t off = ((size_t)((eg * 256 + ks) * 64 + l)) * 16;
    *(int4*)(ws + off)           = o1.q;
    *(int4*)(ws + 2097152 + off) = o2.q;
}

// ============================================================================
// Main kernel v2: 512 blocks x 512 threads (2 blocks/CU). Block = 32 tokens x
// 256 experts; wave eg (0..7) owns 32 experts, full 32 tokens.
// A path: X staged per 128-k slice: global fp32 (nontemporal; each line read
// exactly once device-wide) -> fp16 2-level split ONCE -> LDS in A-fragment
// order; waves ds_read_b128 fragments (conflict-free stride-1).
// B path: W frags from ws (4 MB, L2-resident; X nt-loads don't evict it),
// 4-deep register ring.
// Numerics (round-5/7-proven class): x1w1 -> acc_hi, drained to fp32 tot every
// 8 K-steps (chunked => no long full-magnitude rounding chains);
// x1w2 + x2w1 -> acc_rest chain (2^-11 scale). ~1e-6 logit RMS.
// LDS: XA (2 buf x 2 lvl x 8 ks x 64 lanes x 16 B = 32 KB) aliased by SC
// (256x32 f32 = 32 KB) after the K-loop.
// ============================================================================
__global__ __launch_bounds__(512, 4) void moe_mfma_v2(
    const float* __restrict__ X, const char* __restrict__ ws,
    const float* __restrict__ bias, float* __restrict__ out, int T)
{
    __shared__ __align__(16) char SM[32768];
    float* SC = (float*)SM;          // epilogue alias

    const int tid = threadIdx.x;
    const int l   = tid & 63;
    const int eg  = tid >> 6;        // wave id = expert tile 0..7
    const int sks = tid >> 6;        // staging: ks-slot within slice (0..7)
    const int m0  = blockIdx.x * 32;

    // XA byte address: ((buf*2 + lvl)*8 + ks)*64*16 + lane*16
#define XA_OFF(buf, lvl, ks) ((((buf) * 2 + (lvl)) * 8 + (ks)) * 1024)

    // staging source: token = l&31, k-offset in slice = sks*16 + 8*(l>>5)
    const float* Xs_base = X + (size_t)(m0 + (l & 31)) * H + sks * 16 + 8 * (l >> 5);
    const char*  bp      = ws + (size_t)eg * 262144 + (size_t)l * 16;

    f32x16 acc_hi, acc_rest, tot;
#pragma unroll
    for (int r = 0; r < 16; ++r) { acc_hi[r] = 0.f; acc_rest[r] = 0.f; tot[r] = 0.f; }

    f32x4 xr0, xr1;
    union BF { int4 q; f16x8 v; };
    BF rb[4][2];                     // 4-deep ring x 2 levels

#define XISSUE(s)                                                          \
    {   const float* p_ = Xs_base + (size_t)(s) * 128;                     \
        xr0 = __builtin_nontemporal_load((const f32x4*)p_);                \
        xr1 = __builtin_nontemporal_load((const f32x4*)(p_ + 4)); }

#define XWRITE(buf)                                                       \
    {   union { int4 q; _Float16 h[8]; } w1_, w2_;                        \
        _Pragma("unroll")                                                  \
        for (int j = 0; j < 8; ++j) {                                      \
            const float x_ = (j < 4) ? xr0[j] : xr1[j - 4];                \
            const _Float16 h1_ = (_Float16)x_;                             \
            w1_.h[j] = h1_;                                                \
            w2_.h[j] = (_Float16)(x_ - (float)h1_);                        \
        }                                                                  \
        *(int4*)(SM + XA_OFF(buf, 0, sks) + l * 16) = w1_.q;               \
        *(int4*)(SM + XA_OFF(buf, 1, sks) + l * 16) = w2_.q; }

    // prologue: stage slice 0, issue slice 1, prime B ring
    XISSUE(0)
    XWRITE(0)
    __syncthreads();
    XISSUE(1)
#pragma unroll
    for (int i = 0; i < 4; ++i) {
        rb[i][0].q = *(const int4*)(bp + (size_t)i * 1024);
        rb[i][1].q = *(const int4*)(bp + 2097152 + (size_t)i * 1024);
    }

    int cur = 0;
    for (int s = 0; s < 32; ++s) {
        const int kb = s * 8;
#pragma unroll
        for (int i = 0; i < 8; ++i) {
            union { int4 q; f16x8 v; } a1, a2;
            a1.q = *(const int4*)(SM + XA_OFF(cur, 0, i) + l * 16);
            a2.q = *(const int4*)(SM + XA_OFF(cur, 1, i) + l * 16);
            acc_hi = __builtin_amdgcn_mfma_f32_32x32x16_f16(
                a1.v, rb[i & 3][0].v, acc_hi, 0, 0, 0);
            acc_rest = __builtin_amdgcn_mfma_f32_32x32x16_f16(
                a1.v, rb[i & 3][1].v, acc_rest, 0, 0, 0);
            acc_rest = __builtin_amdgcn_mfma_f32_32x32x16_f16(
                a2.v, rb[i & 3][0].v, acc_rest, 0, 0, 0);
            const int kn = kb + i + 4;
            if (kn < 256) {
                rb[i & 3][0].q = *(const int4*)(bp + (size_t)kn * 1024);
                rb[i & 3][1].q = *(const int4*)(bp + 2097152 + (size_t)kn * 1024);
            }
        }
        // drain K=128 chunk into fp32 totals (32 full-magnitude adds overall)
#pragma unroll
        for (int r = 0; r < 16; ++r) { tot[r] += acc_hi[r]; acc_hi[r] = 0.f; }
        if (s + 1 < 32) {
            XWRITE(cur ^ 1)          // waits xr (vmcnt counted), writes other buf
            __syncthreads();
            if (s + 2 < 32) XISSUE(s + 2)
            cur ^= 1;
        }
    }
#undef XISSUE
#undef XWRITE

    // ---- epilogue: SC aliases XA; barrier separates last reads from writes
    __syncthreads();
    {
        const int e = 32 * eg + (l & 31);
        const float be = bias[e];
#pragma unroll
        for (int r = 0; r < 16; ++r) {
            const int ti = (r & 3) + 8 * (r >> 2) + 4 * (l >> 5);
            const float logit = (tot[r] + acc_rest[r]) * INV_WSCALE;
            const float sv = 1.0f / (1.0f + expf(-logit));
            SC[e * 32 + (ti ^ (e & 31))] = sv + be;
        }
    }
    __syncthreads();

    if (tid < 32) {
        const int t = tid;
        float gs[NGROUP];
#pragma unroll
        for (int g = 0; g < NGROUP; ++g) {
            float m1 = -1e30f, m2 = -1e30f;
            for (int j = 0; j < 32; ++j) {
                const int e = g * 32 + j;
                const float v = SC[e * 32 + (t ^ (e & 31))];
                if (v > m1) { m2 = m1; m1 = v; }
                else if (v > m2) { m2 = v; }
            }
            gs[g] = m1 + m2;
        }
        unsigned gmask = 0;
        for (int r = 0; r < TOPKG; ++r) {
            int bi = 0; float bv = -1e30f;
#pragma unroll
            for (int g = 0; g < NGROUP; ++g)
                if (!((gmask >> g) & 1u) && gs[g] > bv) { bv = gs[g]; bi = g; }
            gmask |= (1u << bi);
        }
        int glist[TOPKG], ng = 0;
#pragma unroll
        for (int g = 0; g < NGROUP; ++g)
            if ((gmask >> g) & 1u) glist[ng++] = g;
        int eidx[TOPK]; float sval[TOPK];
        unsigned cmask[TOPKG] = {0u, 0u, 0u, 0u};
        float wsum = 0.f;
        for (int r = 0; r < TOPK; ++r) {
            float bv = -1e30f; int bgi = 0, bj = 0;
            for (int gi = 0; gi < TOPKG; ++gi) {
                const int g = glist[gi];
                for (int j = 0; j < 32; ++j) {
                    if ((cmask[gi] >> j) & 1u) continue;
                    const int e = g * 32 + j;
                    const float v = SC[e * 32 + (t ^ (e & 31))];
                    if (v > bv) { bv = v; bgi = gi; bj = j; }
                }
            }
            cmask[bgi] |= (1u << bj);
            const int e = glist[bgi] * 32 + bj;
            eidx[r] = e;
            const float sig = bv - bias[e];
            sval[r] = sig; wsum += sig;
        }
        const float scale = ROUTED_SCALING / (wsum + 1e-20f);
        const size_t gt = (size_t)(m0 + t);
#pragma unroll
        for (int r = 0; r < TOPK; ++r) {
            out[gt * TOPK + r] = (float)eidx[r];
            out[(size_t)T * TOPK + gt * TOPK + r] = sval[r] * scale;
        }
    }
}

// ============================================================================
// Fallback (verified round-3 fp32 kernel) if ws is too small for the split-W.
// ============================================================================
#define BMF 32
#define BKF 32
#define WS_STRIDE 388
#define XS_STRIDE 36
#define WS_FLOATS (BKF * WS_STRIDE)
#define SMEM_FLOATS (WS_FLOATS + BKF * XS_STRIDE)

__global__ __launch_bounds__(256, 2) void moe_gate_f32(
    const float* __restrict__ X, const float* __restrict__ W,
    const float* __restrict__ bias, float* __restrict__ out, int T)
{
    __shared__ float smem[SMEM_FLOATS];
    float* Ws = smem;
    float* Xs = smem + WS_FLOATS;
    float* SC = smem;
    const int tid = threadIdx.x;
    const int tq  = tid >> 5;
    const int tx  = tid & 31;
    const int m0  = blockIdx.x * BMF;
    const int q  = tid & 7;
    const int sx = tid >> 3;
    float acc[4][8];
#pragma unroll
    for (int r = 0; r < 4; ++r)
#pragma unroll
        for (int c = 0; c < 8; ++c) acc[r][c] = 0.f;
    float4 xr, wr[8];
    const float* Xbase = X + (size_t)(m0 + sx) * H + 4 * q;
    const float* Wbase = W + (size_t)sx * H + 4 * q;
    auto loadTile = [&](int k0) {
        xr = *(const float4*)(Xbase + k0);
#pragma unroll
        for (int i = 0; i < 8; ++i)
            wr[i] = *(const float4*)(Wbase + (size_t)(32 * i) * H + k0);
    };
    auto storeTile = [&]() {
        Xs[(4 * q + 0) * XS_STRIDE + sx] = xr.x;
        Xs[(4 * q + 1) * XS_STRIDE + sx] = xr.y;
        Xs[(4 * q + 2) * XS_STRIDE + sx] = xr.z;
        Xs[(4 * q + 3) * XS_STRIDE + sx] = xr.w;
#pragma unroll
        for (int i = 0; i < 8; ++i) {
            const int e = sx + 32 * i;
            const int col = 12 * (e >> 3) + (e & 7);
            Ws[(4 * q + 0) * WS_STRIDE + col] = wr[i].x;
            Ws[(4 * q + 1) * WS_STRIDE + col] = wr[i].y;
            Ws[(4 * q + 2) * WS_STRIDE + col] = wr[i].z;
            Ws[(4 * q + 3) * WS_STRIDE + col] = wr[i].w;
        }
    };
    loadTile(0);
    for (int k0 = 0; k0 < H; k0 += BKF) {
        storeTile();
        __syncthreads();
        if (k0 + BKF < H) loadTile(k0 + BKF);
#pragma unroll 8
        for (int kk = 0; kk < BKF; ++kk) {
            float a[4], b[8];
            *(float4*)&a[0] = *(const float4*)&Xs[kk * XS_STRIDE + 4 * tq];
            *(float4*)&b[0] = *(const float4*)&Ws[kk * WS_STRIDE + 12 * tx];
            *(float4*)&b[4] = *(const float4*)&Ws[kk * WS_STRIDE + 12 * tx + 4];
#pragma unroll
            for (int r = 0; r < 4; ++r)
#pragma unroll
                for (int c = 0; c < 8; ++c)
                    acc[r][c] = fmaf(a[r], b[c], acc[r][c]);
        }
        __syncthreads();
    }
#pragma unroll
    for (int c = 0; c < 8; ++c) {
        const int e = 8 * tx + c;
        const float be = bias[e];
#pragma unroll
        for (int r = 0; r < 4; ++r) {
            const int t = 4 * tq + r;
            const float s = 1.0f / (1.0f + expf(-acc[r][c]));
            SC[e * 32 + (t ^ tx)] = s + be;
        }
    }
    __syncthreads();
    if (tid < BMF) {
        const int t = tid;
        float gs[NGROUP];
#pragma unroll
        for (int g = 0; g < NGROUP; ++g) {
            float m1 = -1e30f, m2 = -1e30f;
            for (int j = 0; j < 32; ++j) {
                const int e = g * 32 + j;
                const float v = SC[e * 32 + (t ^ (e >> 3))];
                if (v > m1) { m2 = m1; m1 = v; }
                else if (v > m2) { m2 = v; }
            }
            gs[g] = m1 + m2;
        }
        unsigned gmask = 0;
        for (int r = 0; r < TOPKG; ++r) {
            int bi = 0; float bv = -1e30f;
#pragma unroll
            for (int g = 0; g < NGROUP; ++g)
                if (!((gmask >> g) & 1u) && gs[g] > bv) { bv = gs[g]; bi = g; }
            gmask |= (1u << bi);
        }
        int glist[TOPKG], ng = 0;
#pragma unroll
        for (int g = 0; g < NGROUP; ++g)
            if ((gmask >> g) & 1u) glist[ng++] = g;
        int eidx[TOPK]; float sval[TOPK];
        unsigned cmask[TOPKG] = {0u, 0u, 0u, 0u};
        float wsum = 0.f;
        for (int r = 0; r < TOPK; ++r) {
            float bv = -1e30f; int bgi = 0, bj = 0;
            for (int gi = 0; gi < TOPKG; ++gi) {
                const int g = glist[gi];
                for (int j = 0; j < 32; ++j) {
                    if ((cmask[gi] >> j) & 1u) continue;
                    const int e = g * 32 + j;
                    const float v = SC[e * 32 + (t ^ (e >> 3))];
                    if (v > bv) { bv = v; bgi = gi; bj = j; }
                }
            }
            cmask[bgi] |= (1u << bj);
            const int e = glist[bgi] * 32 + bj;
            eidx[r] = e;
            const float sig = bv - bias[e];
            sval[r] = sig; wsum += sig;
        }
        const float scale = ROUTED_SCALING / (wsum + 1e-20f);
        const size_t gt = (size_t)(m0 + t);
#pragma unroll
        for (int r = 0; r < TOPK; ++r) {
            out[gt * TOPK + r] = (float)eidx[r];
            out[(size_t)T * TOPK + gt * TOPK + r] = sval[r] * scale;
        }
    }
}

extern "C" void kernel_launch(void* const* d_in, const int* in_sizes, int n_in,
                              void* d_out, int out_size, void* d_ws, size_t ws_size,
                              hipStream_t stream) {
    const float* X = (const float*)d_in[0];
    const float* W = (const float*)d_in[1];
    const float* B = (const float*)d_in[2];
    float* out = (float*)d_out;
    const int T = in_sizes[0] / H;            // 16384
    if (ws_size >= (size_t)4 * 1024 * 1024) {
        wsplit_kernel<<<512, 256, 0, stream>>>(W, (char*)d_ws);
        moe_mfma_v2<<<T / 32, 512, 0, stream>>>(X, (const char*)d_ws, B, out, T);
    } else {
        moe_gate_f32<<<T / 32, 256, 0, stream>>>(X, W, B, out, T);
    }
}

// Round 9
// 229.159 us; speedup vs baseline: 2.6234x; 1.0764x over previous
//
#include <hip/hip_runtime.h>
#include <hip/hip_bf16.h>

#define H 4096
#define NEXP 256
#define TOPK 8
#define NGROUP 8
#define TOPKG 4
#define ROUTED_SCALING 2.5f
#define WSCALE 1024.0f
#define INV_WSCALE (1.0f / 1024.0f)

typedef __attribute__((ext_vector_type(8)))  _Float16 f16x8;
typedef __attribute__((ext_vector_type(16))) float    f32x16;
typedef __attribute__((ext_vector_type(4)))  float    f32x4;

// ============================================================================
// Pre-kernel: split W*1024 [256][4096] fp32 into 2 fp16 levels (hi + exact
// residual), stored in mfma_f32_32x32x16_f16 B-fragment order.
//   level v at byte offset v*2097152 (2 MB each, 4 MB total)
//   frag addr = v*2097152 + ((etile*256 + ks)*64 + lane)*16
//   lane l holds W[etile*32 + (l&31)][16*ks + 8*(l>>5) + j], j=0..7
// ============================================================================
__global__ __launch_bounds__(256) void wsplit_kernel(
    const float* __restrict__ W, char* __restrict__ ws)
{
    const int t  = blockIdx.x * 256 + threadIdx.x;   // 0..131071
    const int l  = t & 63;
    const int ks = (t >> 6) & 255;
    const int eg = t >> 14;                          // expert tile 0..7
    const int expert = eg * 32 + (l & 31);
    const int k0 = ks * 16 + (l >> 5) * 8;
    const float* src = W + (size_t)expert * H + k0;
    float xf[8];
    *(float4*)&xf[0] = *(const float4*)(src);
    *(float4*)&xf[4] = *(const float4*)(src + 4);
    union { _Float16 h[8]; int4 q; } o1, o2;
#pragma unroll
    for (int j = 0; j < 8; ++j) {
        const float x = xf[j] * WSCALE;
        const _Float16 h1 = (_Float16)x;
        o1.h[j] = h1;
        o2.h[j] = (_Float16)(x - (float)h1);
    }
    const size_t off = ((size_t)((eg * 256 + ks) * 64 + l)) * 16;
    *(int4*)(ws + off)           = o1.q;
    *(int4*)(ws + 2097152 + off) = o2.q;
}

// ============================================================================
// Main kernel v3: 256 blocks x 512 threads (1 block/CU). Block = 64 tokens x
// 256 experts; wave eg owns expert tile eg (32 exp) x 64 tokens (2 M-tiles).
// B traffic: 256 blocks x 4 MB = 1 GB (half of v2) - the v2 bottleneck.
// K-loop slice boundary uses lgkmcnt-only + raw s_barrier (no vmcnt drain:
// B-ring prefetches stay in flight across slices, T4).
// Numerics (proven r5/7/8): x1w1 -> acc_hi drained to fp32 tot every 8 steps;
// x1w2 + x2w1 chained in acc_rest (2^-11 scale).
// LDS 64 KB: XA[2buf][2lvl][8ks][2m][64lanes]x16B aliased by SC[256][64] f32.
// ============================================================================
__global__ __launch_bounds__(512, 2) void moe_mfma_v3(
    const float* __restrict__ X, const char* __restrict__ ws,
    const float* __restrict__ bias, float* __restrict__ out, int T)
{
    __shared__ __align__(16) char SM[65536];
    float* SC = (float*)SM;          // epilogue alias

    const int tid = threadIdx.x;
    const int l   = tid & 63;
    const int eg  = tid >> 6;        // wave id = expert tile 0..7
    const int sks = tid >> 6;        // staging: ks-slot within slice (0..7)
    const int m0  = blockIdx.x * 64;

#define XA_OFF(buf, lvl, ks, m) (((((buf) * 2 + (lvl)) * 8 + (ks)) * 2 + (m)) * 1024)

    // staging source: token(m) = m0 + 32m + (l&31); k-off = sks*16 + 8*(l>>5)
    const float* Xs_base = X + (size_t)(m0 + (l & 31)) * H + sks * 16 + 8 * (l >> 5);
    const char*  bp      = ws + (size_t)eg * 262144 + (size_t)l * 16;

    f32x16 acc_hi[2], acc_rest[2], tot[2];
#pragma unroll
    for (int m = 0; m < 2; ++m)
#pragma unroll
        for (int r = 0; r < 16; ++r) {
            acc_hi[m][r] = 0.f; acc_rest[m][r] = 0.f; tot[m][r] = 0.f;
        }

    f32x4 xr[2][2];                  // [m][half]
    union BF { int4 q; f16x8 v; };
    BF rb[4][2];                     // 4-deep ring x 2 levels

#define XISSUE(s)                                                          \
    { _Pragma("unroll")                                                    \
      for (int m = 0; m < 2; ++m) {                                        \
        const float* p_ = Xs_base + (size_t)(s) * 128 + (size_t)m * 32 * H;\
        xr[m][0] = __builtin_nontemporal_load((const f32x4*)p_);           \
        xr[m][1] = __builtin_nontemporal_load((const f32x4*)(p_ + 4));     \
      } }

#define XWRITE(buf)                                                       \
    { _Pragma("unroll")                                                    \
      for (int m = 0; m < 2; ++m) {                                        \
        union { int4 q; _Float16 h[8]; } w1_, w2_;                        \
        _Pragma("unroll")                                                  \
        for (int j = 0; j < 8; ++j) {                                      \
            const float x_ = (j < 4) ? xr[m][0][j] : xr[m][1][j - 4];      \
            const _Float16 h1_ = (_Float16)x_;                             \
            w1_.h[j] = h1_;                                                \
            w2_.h[j] = (_Float16)(x_ - (float)h1_);                        \
        }                                                                  \
        *(int4*)(SM + XA_OFF(buf, 0, sks, m) + l * 16) = w1_.q;            \
        *(int4*)(SM + XA_OFF(buf, 1, sks, m) + l * 16) = w2_.q;            \
      } }

// slice barrier WITHOUT vmcnt drain: own-wave LDS ops complete, then barrier;
// in-flight global (B-ring / xr) loads survive.
#define SLICE_BARRIER()                                                    \
    { asm volatile("s_waitcnt lgkmcnt(0)" ::: "memory");                   \
      __builtin_amdgcn_s_barrier();                                        \
      asm volatile("" ::: "memory"); }

    // prologue: stage slice 0, issue slice 1, prime B ring
    XISSUE(0)
    XWRITE(0)
    __syncthreads();
    XISSUE(1)
#pragma unroll
    for (int i = 0; i < 4; ++i) {
        rb[i][0].q = *(const int4*)(bp + (size_t)i * 1024);
        rb[i][1].q = *(const int4*)(bp + 2097152 + (size_t)i * 1024);
    }

    int cur = 0;
    for (int s = 0; s < 32; ++s) {
        const int kb = s * 8;
#pragma unroll
        for (int i = 0; i < 8; ++i) {
            union { int4 q; f16x8 v; } a1[2], a2[2];
#pragma unroll
            for (int m = 0; m < 2; ++m) {
                a1[m].q = *(const int4*)(SM + XA_OFF(cur, 0, i, m) + l * 16);
                a2[m].q = *(const int4*)(SM + XA_OFF(cur, 1, i, m) + l * 16);
            }
#pragma unroll
            for (int m = 0; m < 2; ++m) {
                acc_hi[m] = __builtin_amdgcn_mfma_f32_32x32x16_f16(
                    a1[m].v, rb[i & 3][0].v, acc_hi[m], 0, 0, 0);
                acc_rest[m] = __builtin_amdgcn_mfma_f32_32x32x16_f16(
                    a1[m].v, rb[i & 3][1].v, acc_rest[m], 0, 0, 0);
                acc_rest[m] = __builtin_amdgcn_mfma_f32_32x32x16_f16(
                    a2[m].v, rb[i & 3][0].v, acc_rest[m], 0, 0, 0);
            }
            const int kn = kb + i + 4;
            if (kn < 256) {
                rb[i & 3][0].q = *(const int4*)(bp + (size_t)kn * 1024);
                rb[i & 3][1].q = *(const int4*)(bp + 2097152 + (size_t)kn * 1024);
            }
        }
        // drain K=128 chunk into fp32 totals
#pragma unroll
        for (int m = 0; m < 2; ++m)
#pragma unroll
            for (int r = 0; r < 16; ++r) { tot[m][r] += acc_hi[m][r]; acc_hi[m][r] = 0.f; }
        if (s + 1 < 32) {
            XWRITE(cur ^ 1)          // waits xr via compiler vmcnt, writes other buf
            SLICE_BARRIER()
            if (s + 2 < 32) XISSUE(s + 2)
            cur ^= 1;
        }
    }
#undef XISSUE
#undef XWRITE
#undef SLICE_BARRIER

    // ---- epilogue: SC aliases XA ----
    __syncthreads();
    {
        const int e = 32 * eg + (l & 31);
        const float be = bias[e];
#pragma unroll
        for (int m = 0; m < 2; ++m)
#pragma unroll
            for (int r = 0; r < 16; ++r) {
                const int ti = 32 * m + (r & 3) + 8 * (r >> 2) + 4 * (l >> 5);
                const float logit = (tot[m][r] + acc_rest[m][r]) * INV_WSCALE;
                const float sv = 1.0f / (1.0f + expf(-logit));
                SC[e * 64 + (ti ^ (e & 31))] = sv + be;
            }
    }
    __syncthreads();

    if (tid < 64) {
        const int t = tid;
        float gs[NGROUP];
#pragma unroll
        for (int g = 0; g < NGROUP; ++g) {
            float m1 = -1e30f, m2 = -1e30f;
            for (int j = 0; j < 32; ++j) {
                const int e = g * 32 + j;
                const float v = SC[e * 64 + (t ^ (e & 31))];
                if (v > m1) { m2 = m1; m1 = v; }
                else if (v > m2) { m2 = v; }
            }
            gs[g] = m1 + m2;
        }
        unsigned gmask = 0;
        for (int r = 0; r < TOPKG; ++r) {
            int bi = 0; float bv = -1e30f;
#pragma unroll
            for (int g = 0; g < NGROUP; ++g)
                if (!((gmask >> g) & 1u) && gs[g] > bv) { bv = gs[g]; bi = g; }
            gmask |= (1u << bi);
        }
        int glist[TOPKG], ng = 0;
#pragma unroll
        for (int g = 0; g < NGROUP; ++g)
            if ((gmask >> g) & 1u) glist[ng++] = g;
        int eidx[TOPK]; float sval[TOPK];
        unsigned cmask[TOPKG] = {0u, 0u, 0u, 0u};
        float wsum = 0.f;
        for (int r = 0; r < TOPK; ++r) {
            float bv = -1e30f; int bgi = 0, bj = 0;
            for (int gi = 0; gi < TOPKG; ++gi) {
                const int g = glist[gi];
                for (int j = 0; j < 32; ++j) {
                    if ((cmask[gi] >> j) & 1u) continue;
                    const int e = g * 32 + j;
                    const float v = SC[e * 64 + (t ^ (e & 31))];
                    if (v > bv) { bv = v; bgi = gi; bj = j; }
                }
            }
            cmask[bgi] |= (1u << bj);
            const int e = glist[bgi] * 32 + bj;
            eidx[r] = e;
            const float sig = bv - bias[e];
            sval[r] = sig; wsum += sig;
        }
        const float scale = ROUTED_SCALING / (wsum + 1e-20f);
        const size_t gt = (size_t)(m0 + t);
#pragma unroll
        for (int r = 0; r < TOPK; ++r) {
            out[gt * TOPK + r] = (float)eidx[r];
            out[(size_t)T * TOPK + gt * TOPK + r] = sval[r] * scale;
        }
    }
}

// ============================================================================
// Fallback (verified round-3 fp32 kernel) if ws is too small for the split-W.
// ============================================================================
#define BMF 32
#define BKF 32
#define WS_STRIDE 388
#define XS_STRIDE 36
#define WS_FLOATS (BKF * WS_STRIDE)
#define SMEM_FLOATS (WS_FLOATS + BKF * XS_STRIDE)

__global__ __launch_bounds__(256, 2) void moe_gate_f32(
    const float* __restrict__ X, const float* __restrict__ W,
    const float* __restrict__ bias, float* __restrict__ out, int T)
{
    __shared__ float smem[SMEM_FLOATS];
    float* Ws = smem;
    float* Xs = smem + WS_FLOATS;
    float* SC = smem;
    const int tid = threadIdx.x;
    const int tq  = tid >> 5;
    const int tx  = tid & 31;
    const int m0  = blockIdx.x * BMF;
    const int q  = tid & 7;
    const int sx = tid >> 3;
    float acc[4][8];
#pragma unroll
    for (int r = 0; r < 4; ++r)
#pragma unroll
        for (int c = 0; c < 8; ++c) acc[r][c] = 0.f;
    float4 xr, wr[8];
    const float* Xbase = X + (size_t)(m0 + sx) * H + 4 * q;
    const float* Wbase = W + (size_t)sx * H + 4 * q;
    auto loadTile = [&](int k0) {
        xr = *(const float4*)(Xbase + k0);
#pragma unroll
        for (int i = 0; i < 8; ++i)
            wr[i] = *(const float4*)(Wbase + (size_t)(32 * i) * H + k0);
    };
    auto storeTile = [&]() {
        Xs[(4 * q + 0) * XS_STRIDE + sx] = xr.x;
        Xs[(4 * q + 1) * XS_STRIDE + sx] = xr.y;
        Xs[(4 * q + 2) * XS_STRIDE + sx] = xr.z;
        Xs[(4 * q + 3) * XS_STRIDE + sx] = xr.w;
#pragma unroll
        for (int i = 0; i < 8; ++i) {
            const int e = sx + 32 * i;
            const int col = 12 * (e >> 3) + (e & 7);
            Ws[(4 * q + 0) * WS_STRIDE + col] = wr[i].x;
            Ws[(4 * q + 1) * WS_STRIDE + col] = wr[i].y;
            Ws[(4 * q + 2) * WS_STRIDE + col] = wr[i].z;
            Ws[(4 * q + 3) * WS_STRIDE + col] = wr[i].w;
        }
    };
    loadTile(0);
    for (int k0 = 0; k0 < H; k0 += BKF) {
        storeTile();
        __syncthreads();
        if (k0 + BKF < H) loadTile(k0 + BKF);
#pragma unroll 8
        for (int kk = 0; kk < BKF; ++kk) {
            float a[4], b[8];
            *(float4*)&a[0] = *(const float4*)&Xs[kk * XS_STRIDE + 4 * tq];
            *(float4*)&b[0] = *(const float4*)&Ws[kk * WS_STRIDE + 12 * tx];
            *(float4*)&b[4] = *(const float4*)&Ws[kk * WS_STRIDE + 12 * tx + 4];
#pragma unroll
            for (int r = 0; r < 4; ++r)
#pragma unroll
                for (int c = 0; c < 8; ++c)
                    acc[r][c] = fmaf(a[r], b[c], acc[r][c]);
        }
        __syncthreads();
    }
#pragma unroll
    for (int c = 0; c < 8; ++c) {
        const int e = 8 * tx + c;
        const float be = bias[e];
#pragma unroll
        for (int r = 0; r < 4; ++r) {
            const int t = 4 * tq + r;
            const float s = 1.0f / (1.0f + expf(-acc[r][c]));
            SC[e * 32 + (t ^ tx)] = s + be;
        }
    }
    __syncthreads();
    if (tid < BMF) {
        const int t = tid;
        float gs[NGROUP];
#pragma unroll
        for (int g = 0; g < NGROUP; ++g) {
            float m1 = -1e30f, m2 = -1e30f;
            for (int j = 0; j < 32; ++j) {
                const int e = g * 32 + j;
                const float v = SC[e * 32 + (t ^ (e >> 3))];
                if (v > m1) { m2 = m1; m1 = v; }
                else if (v > m2) { m2 = v; }
            }
            gs[g] = m1 + m2;
        }
        unsigned gmask = 0;
        for (int r = 0; r < TOPKG; ++r) {
            int bi = 0; float bv = -1e30f;
#pragma unroll
            for (int g = 0; g < NGROUP; ++g)
                if (!((gmask >> g) & 1u) && gs[g] > bv) { bv = gs[g]; bi = g; }
            gmask |= (1u << bi);
        }
        int glist[TOPKG], ng = 0;
#pragma unroll
        for (int g = 0; g < NGROUP; ++g)
            if ((gmask >> g) & 1u) glist[ng++] = g;
        int eidx[TOPK]; float sval[TOPK];
        unsigned cmask[TOPKG] = {0u, 0u, 0u, 0u};
        float wsum = 0.f;
        for (int r = 0; r < TOPK; ++r) {
            float bv = -1e30f; int bgi = 0, bj = 0;
            for (int gi = 0; gi < TOPKG; ++gi) {
                const int g = glist[gi];
                for (int j = 0; j < 32; ++j) {
                    if ((cmask[gi] >> j) & 1u) continue;
                    const int e = g * 32 + j;
                    const float v = SC[e * 32 + (t ^ (e >> 3))];
                    if (v > bv) { bv = v; bgi = gi; bj = j; }
                }
            }
            cmask[bgi] |= (1u << bj);
            const int e = glist[bgi] * 32 + bj;
            eidx[r] = e;
            const float sig = bv - bias[e];
            sval[r] = sig; wsum += sig;
        }
        const float scale = ROUTED_SCALING / (wsum + 1e-20f);
        const size_t gt = (size_t)(m0 + t);
#pragma unroll
        for (int r = 0; r < TOPK; ++r) {
            out[gt * TOPK + r] = (float)eidx[r];
            out[(size_t)T * TOPK + gt * TOPK + r] = sval[r] * scale;
        }
    }
}

extern "C" void kernel_launch(void* const* d_in, const int* in_sizes, int n_in,
                              void* d_out, int out_size, void* d_ws, size_t ws_size,
                              hipStream_t stream) {
    const float* X = (const float*)d_in[0];
    const float* W = (const float*)d_in[1];
    const float* B = (const float*)d_in[2];
    float* out = (float*)d_out;
    const int T = in_sizes[0] / H;            // 16384
    if (ws_size >= (size_t)4 * 1024 * 1024) {
        wsplit_kernel<<<512, 256, 0, stream>>>(W, (char*)d_ws);
        moe_mfma_v3<<<T / 64, 512, 0, stream>>>(X, (const char*)d_ws, B, out, T);
    } else {
        moe_gate_f32<<<T / 32, 256, 0, stream>>>(X, W, B, out, T);
    }
}